// Round 10
// baseline (181.199 us; speedup 1.0000x reference)
//
#include <hip/hip_runtime.h>
#include <hip/hip_bf16.h>

// Problem constants
#define Bn 2
#define Tdim 2048
#define Ddim 1024
#define Hn 16
#define HD 64

typedef unsigned short u16;
typedef unsigned int u32;
typedef __attribute__((ext_vector_type(8))) __bf16 bf16x8;
typedef __attribute__((ext_vector_type(4))) float f32x4;
typedef __attribute__((ext_vector_type(16))) float f32x16;
typedef __attribute__((ext_vector_type(4))) u32 u32x4;

struct alignas(8) U16x4 { u16 x, y, z, w; };

__device__ __forceinline__ u16 f2bf(float f) {
  union { float f; u32 i; } v; v.f = f;
  u32 x = v.i;
  u32 r = (x + 0x7fffu + ((x >> 16) & 1u)) >> 16;
  return (u16)r;
}
__device__ __forceinline__ float bf2f(u16 u) {
  union { u32 i; float f; } v; v.i = ((u32)u) << 16; return v.f;
}

// packed f32->bf16 convert: dst.lo16 = bf16(a), dst.hi16 = bf16(b) (RNE)
__device__ __forceinline__ u32 cvtpk_bf16(float a, float b) {
  u32 d;
  asm("v_cvt_pk_bf16_f32 %0, %1, %2" : "=v"(d) : "v"(a), "v"(b));
  return d;
}

// async global->LDS, 16B per lane; LDS dest = wave-uniform base + lane*16
__device__ __forceinline__ void cp16(const u16* g, u16* l) {
  __builtin_amdgcn_global_load_lds(
      (const __attribute__((address_space(1))) u32*)g,
      (__attribute__((address_space(3))) u32*)l, 16, 0, 0);
}

__device__ __forceinline__ f32x4 mfma16(bf16x8 a, bf16x8 b, f32x4 c) {
  return __builtin_amdgcn_mfma_f32_16x16x32_bf16(a, b, c, 0, 0, 0);
}
__device__ __forceinline__ f32x16 mfma32(bf16x8 a, bf16x8 b, f32x16 c) {
  return __builtin_amdgcn_mfma_f32_32x32x16_bf16(a, b, c, 0, 0, 0);
}

// ---------------- fused preprocessing: weight transpose (z=0..3) + X convert (z=4) ----------------
__global__ __launch_bounds__(256) void preproc_k(
    const float* __restrict__ x, u16* __restrict__ Xb,
    const float* __restrict__ s0, const float* __restrict__ s1,
    const float* __restrict__ s2, const float* __restrict__ s3,
    u16* __restrict__ dstW) {
  const int tx = threadIdx.x, ty = threadIdx.y;
  if (blockIdx.z == 4) {
    // X f32 -> bf16, 16 elems/thread
    const int tid = ty * 32 + tx;
    const int i = ((blockIdx.y * 32 + blockIdx.x) * 256 + tid) * 16;
#pragma unroll
    for (int c = 0; c < 2; c++) {
      u16 t[8];
#pragma unroll
      for (int j = 0; j < 8; j++) t[j] = f2bf(x[i + c * 8 + j]);
      *(bf16x8*)&Xb[i + c * 8] = *(const bf16x8*)t;
    }
    return;
  }
  const float* src = (blockIdx.z == 0) ? s0 : (blockIdx.z == 1) ? s1
                   : (blockIdx.z == 2) ? s2 : s3;
  u16* d = dstW + (size_t)blockIdx.z * Ddim * Ddim;
  __shared__ u16 tile[32][33];
  const int xx = blockIdx.x * 32 + tx;
  const int y0 = blockIdx.y * 32;
#pragma unroll
  for (int j = 0; j < 32; j += 8) tile[ty + j][tx] = f2bf(src[(size_t)(y0 + ty + j) * Ddim + xx]);
  __syncthreads();
  const int xo = blockIdx.y * 32 + tx;
  const int yo0 = blockIdx.x * 32;
#pragma unroll
  for (int j = 0; j < 32; j += 8) d[(size_t)(yo0 + ty + j) * Ddim + xo] = tile[tx][ty + j];
}

// ---------------- fused QKV projection GEMM: 128x128, BK=64, swizzled LDS ----------------
// z<2 (Q/K) uses SWAPPED MFMA operand order (legal: A/B fragments are
// layout-symmetric for 16x16x32): acc regs then hold 4 consecutive d values
// -> packed U16x4 stores (16x8B) instead of 64 scalar 2B stores.
// z==2 (V^T) keeps the original order (regs = 4 consecutive t, packed along t).
__global__ __launch_bounds__(256, 2) void gemm_qkv(
    const u16* __restrict__ Xb, const u16* __restrict__ WT,
    const float* __restrict__ bq, const float* __restrict__ bk, const float* __restrict__ bv,
    u16* __restrict__ Q, u16* __restrict__ K, u16* __restrict__ Vt) {
  const int flat = blockIdx.x + 32 * (blockIdx.y + 8 * blockIdx.z);
  const int l = (flat & 7) * 96 + (flat >> 3);
  const int lbx = l & 31, lby = (l >> 5) & 7, z = l >> 8;

  const u16* Wt = WT + (size_t)z * Ddim * Ddim;
  const float* bias = (z == 0) ? bq : (z == 1) ? bk : bv;
  u16* QK = (z == 0) ? Q : K;

  __shared__ alignas(16) u16 Alds[128 * 64];
  __shared__ alignas(16) u16 Blds[128 * 64];
  const int tid = threadIdx.x;
  const int w = tid >> 6, lane = tid & 63, ln = lane & 15, quad = lane >> 4;
  const int wm = (w >> 1) * 64, wn = (w & 1) * 64;
  const int tm = lbx * 128, tn = lby * 128;

  f32x4 acc[4][4] = {};

  const int srow = lane >> 3;                    // 0..7
  const int scol = ((lane & 7) ^ srow) * 8;      // inverse swizzle on source
  const u16* ag0 = Xb + (size_t)(tm + w * 32 + srow) * Ddim + scol;
  const u16* bg0 = Wt + (size_t)(tn + w * 32 + srow) * Ddim + scol;

#define QKV_KLOOP(MFMA_EXPR)                                                  \
  for (int k0 = 0; k0 < Ddim; k0 += 64) {                                     \
    __syncthreads();                                                          \
    _Pragma("unroll")                                                         \
    for (int j = 0; j < 4; j++) {                                             \
      cp16(ag0 + (size_t)j * 8 * Ddim + k0, &Alds[(w * 32 + j * 8) * 64]);    \
      cp16(bg0 + (size_t)j * 8 * Ddim + k0, &Blds[(w * 32 + j * 8) * 64]);    \
    }                                                                         \
    __syncthreads();                                                          \
    _Pragma("unroll")                                                         \
    for (int k2 = 0; k2 < 2; k2++) {                                          \
      const int so = ((k2 * 4 + quad) ^ (ln & 7)) * 8;                        \
      bf16x8 af[4], bfr[4];                                                   \
      _Pragma("unroll")                                                       \
      for (int i = 0; i < 4; i++)                                             \
        af[i] = *(const bf16x8*)&Alds[(wm + i * 16 + ln) * 64 + so];          \
      _Pragma("unroll")                                                       \
      for (int i = 0; i < 4; i++)                                             \
        bfr[i] = *(const bf16x8*)&Blds[(wn + i * 16 + ln) * 64 + so];         \
      _Pragma("unroll")                                                       \
      for (int mi = 0; mi < 4; mi++)                                          \
        _Pragma("unroll")                                                     \
        for (int ni = 0; ni < 4; ni++)                                        \
          acc[mi][ni] = MFMA_EXPR;                                            \
    }                                                                         \
  }

  if (z < 2) {
    QKV_KLOOP(mfma16(bfr[ni], af[mi], acc[mi][ni]))
    // epilogue: regs r=0..3 hold consecutive d at fixed t=...+ln
    float bv4[4][4];
#pragma unroll
    for (int ni = 0; ni < 4; ni++)
#pragma unroll
      for (int r = 0; r < 4; r++)
        bv4[ni][r] = bias[tn + wn + ni * 16 + quad * 4 + r];
#pragma unroll
    for (int mi = 0; mi < 4; mi++) {
      const int gm = tm + wm + mi * 16 + ln;
      const int b0 = gm >> 11, t0 = gm & 2047;
#pragma unroll
      for (int ni = 0; ni < 4; ni++) {
        const int gnq = tn + wn + ni * 16 + quad * 4;
        const int hh = gnq >> 6, dd = gnq & 63;
        U16x4 pk;
        pk.x = f2bf(acc[mi][ni][0] + bv4[ni][0]);
        pk.y = f2bf(acc[mi][ni][1] + bv4[ni][1]);
        pk.z = f2bf(acc[mi][ni][2] + bv4[ni][2]);
        pk.w = f2bf(acc[mi][ni][3] + bv4[ni][3]);
        *(U16x4*)&QK[((size_t)(b0 * Hn + hh) * Tdim + t0) * HD + dd] = pk;
      }
    }
  } else {
    QKV_KLOOP(mfma16(af[mi], bfr[ni], acc[mi][ni]))
    // epilogue: regs r=0..3 hold consecutive t at fixed d -> packed along t
#pragma unroll
    for (int mi = 0; mi < 4; mi++) {
#pragma unroll
      for (int ni = 0; ni < 4; ni++) {
        const int gm0 = tm + wm + mi * 16 + quad * 4;
        const int gn = tn + wn + ni * 16 + ln;
        const float bv_ = bias[gn];
        const int hh = gn >> 6, dd = gn & 63;
        const int b0 = gm0 >> 11, t0 = gm0 & 2047;
        U16x4 pk;
        pk.x = f2bf(acc[mi][ni][0] + bv_);
        pk.y = f2bf(acc[mi][ni][1] + bv_);
        pk.z = f2bf(acc[mi][ni][2] + bv_);
        pk.w = f2bf(acc[mi][ni][3] + bv_);
        *(U16x4*)&Vt[((size_t)(b0 * Hn + hh) * HD + dd) * Tdim + t0] = pk;
      }
    }
  }
#undef QKV_KLOOP
}

// ---------------- flash attention v10: double-buffered LDS, ONE barrier/tile ----------------
// Round-9 structure kept (triangle-folded pairing, bh-grouped XCD swizzle,
// 2-way key split). Change: K/V LDS double-buffered (2x33.5KB=67KB, still
// 2 blocks/CU). Per tile: barrier -> issue t+1 global loads -> QK^T+softmax
// (covers load latency) -> ds_write t+1 into buf[c^1] (overlaps PV) -> PV.
// Removes the second barrier and takes the ds_write off the critical path.
#define KSTR 68
#define VSTR 132
#define L2E 1.44269504088896f
__global__ __launch_bounds__(256, 2) void attn_k(
    const u16* __restrict__ Q, const u16* __restrict__ K, const u16* __restrict__ Vt,
    u16* __restrict__ Op, float* __restrict__ lp) {
  __shared__ alignas(16) u16 Klds[2][128 * KSTR];
  __shared__ alignas(16) u16 Vtlds[2][64 * VSTR];

  const int id = blockIdx.x;
  const int xcd = id & 7, slot = id >> 3;
  const int bh = (xcd << 2) | (slot >> 4);
  const int inner = slot & 15;
  const int p = inner >> 1;
  const int s = inner & 1;
  const int tid = threadIdx.x;
  const int w = tid >> 6, lane = tid & 63;
  const int qi = lane & 31, hf = lane >> 5;

  const u16* Qh = Q + (size_t)bh * Tdim * HD;
  const u16* Kh = K + (size_t)bh * Tdim * HD;
  const u16* Vh = Vt + (size_t)bh * HD * Tdim;
  const float slope = exp2f(-0.5f * (float)((bh & 15) + 1));

  const float sl2 = slope * L2E;
  const float c1 = 0.125f * L2E;
  const float f4hf = (float)(4 * hf);
  float sg8[4], slm[4];
#pragma unroll
  for (int g = 0; g < 4; g++) sg8[g] = sl2 * (float)(8 * g);
#pragma unroll
  for (int m = 0; m < 4; m++) slm[m] = sl2 * (float)m;

  const int qbs[2] = {p, 15 - p};
  int K0[2], K1[2];
#pragma unroll
  for (int seg = 0; seg < 2; seg++) {
    const int nk = qbs[seg] + 1;
    const int h0 = (nk + 1) >> 1;
    K0[seg] = s ? h0 : 0;
    K1[seg] = s ? nk : h0;
  }

  // prologue: load first tile into regs, write buffer 0
  bf16x8 kreg[4], vreg[4];
  {
    const int kb = ((K0[0] < K1[0]) ? K0[0] : K0[1]) * 128;
#pragma unroll
    for (int c = 0; c < 4; c++) {
      const int e = c * 2048 + tid * 8;
      kreg[c] = *(const bf16x8*)&Kh[(size_t)(kb + (e >> 6)) * HD + (e & 63)];
      vreg[c] = *(const bf16x8*)&Vh[(size_t)(e >> 7) * Tdim + kb + (e & 127)];
    }
#pragma unroll
    for (int c = 0; c < 4; c++) {
      const int e = c * 2048 + tid * 8;
      *(bf16x8*)&Klds[0][(e >> 6) * KSTR + (e & 63)] = kreg[c];
      *(bf16x8*)&Vtlds[0][(e >> 7) * VSTR + (e & 127)] = vreg[c];
    }
  }
  int cb = 0;  // current LDS buffer

  for (int seg = 0; seg < 2; seg++) {
    const int qb = qbs[seg];
    const int kt0 = K0[seg], kt1 = K1[seg];
    const int nkt = qb + 1;
    const int q0 = qb * 128;
    const int tg = q0 + w * 32 + qi;
    const float tt2 = (slope * (float)tg + 3.0f) * L2E;

    bf16x8 qf[4];
#pragma unroll
    for (int kc = 0; kc < 4; kc++)
      qf[kc] = *(const bf16x8*)&Qh[(size_t)tg * HD + kc * 16 + hf * 8];

    float ls0 = 0.f, ls1 = 0.f;
    f32x16 oacc[2] = {};

    for (int kt = kt0; kt < kt1; kt++) {
      const int kb = kt * 128;
      __syncthreads();  // buf[cb] (tile kt) visible; buf[cb^1] free to fill

      // issue next-tile global loads (retire under QK^T + softmax)
      const int nxt = (kt + 1 < kt1) ? (kt + 1) : ((seg == 0) ? K0[1] : -1);
      if (nxt >= 0) {
        const int kb2 = nxt * 128;
#pragma unroll
        for (int c = 0; c < 4; c++) {
          const int e = c * 2048 + tid * 8;
          kreg[c] = *(const bf16x8*)&Kh[(size_t)(kb2 + (e >> 6)) * HD + (e & 63)];
          vreg[c] = *(const bf16x8*)&Vh[(size_t)(e >> 7) * Tdim + kb2 + (e & 127)];
        }
      }

      // S^T = K Q^T from buf[cb]
      f32x16 st[4] = {};
      __builtin_amdgcn_s_setprio(1);
#pragma unroll
      for (int kc = 0; kc < 4; kc++) {
#pragma unroll
        for (int ni = 0; ni < 4; ni++) {
          bf16x8 kf = *(const bf16x8*)&Klds[cb][(ni * 32 + qi) * KSTR + kc * 16 + hf * 8];
          st[ni] = mfma32(kf, qf[kc], st[ni]);
        }
      }
      __builtin_amdgcn_s_setprio(0);

      const bool diag = (kt == nkt - 1);
      const float fkb = (float)kb + f4hf;
      bf16x8 pfrag[8];
#pragma unroll
      for (int ni = 0; ni < 4; ni++) {
        const float cni = __builtin_fmaf(sl2, fkb + (float)(32 * ni), -tt2);
        float pv[16];
        if (!diag) {
#pragma unroll
          for (int ri = 0; ri < 16; ri++) {
            const float e = __builtin_fmaf(st[ni][ri], c1, cni + sg8[ri >> 2] + slm[ri & 3]);
            const float pp = __builtin_amdgcn_exp2f(e);
            if (ri & 1) ls1 += pp; else ls0 += pp;
            pv[ri] = pp;
          }
        } else {
#pragma unroll
          for (int ri = 0; ri < 16; ri++) {
            const int n = kb + ni * 32 + (ri & 3) + 8 * (ri >> 2) + 4 * hf;
            const float e = __builtin_fmaf(st[ni][ri], c1, cni + sg8[ri >> 2] + slm[ri & 3]);
            float pp = __builtin_amdgcn_exp2f(e);
            if (n > tg) pp = 0.f;
            if (ri & 1) ls1 += pp; else ls0 += pp;
            pv[ri] = pp;
          }
        }
        u32 pk[4][2];
#pragma unroll
        for (int g = 0; g < 4; g++) {
          pk[g][0] = cvtpk_bf16(pv[g * 4 + 0], pv[g * 4 + 1]);
          pk[g][1] = cvtpk_bf16(pv[g * 4 + 2], pv[g * 4 + 3]);
        }
#pragma unroll
        for (int a = 0; a < 2; a++) {
          const u32 snd0 = (hf == 0) ? pk[2 * a + 1][0] : pk[2 * a][0];
          const u32 snd1 = (hf == 0) ? pk[2 * a + 1][1] : pk[2 * a][1];
          const u32 rcv0 = (u32)__shfl_xor((int)snd0, 32);
          const u32 rcv1 = (u32)__shfl_xor((int)snd1, 32);
          u32x4 fr;
          fr.x = (hf == 0) ? pk[2 * a][0] : rcv0;
          fr.y = (hf == 0) ? pk[2 * a][1] : rcv1;
          fr.z = (hf == 0) ? rcv0 : pk[2 * a + 1][0];
          fr.w = (hf == 0) ? rcv1 : pk[2 * a + 1][1];
          pfrag[ni * 2 + a] = *(bf16x8*)&fr;
        }
      }

      // write next tile into buf[cb^1] (overlaps PV; barrier at next iter
      // top makes it visible). Loads have had QK+softmax time to land.
      if (nxt >= 0) {
#pragma unroll
        for (int c = 0; c < 4; c++) {
          const int e = c * 2048 + tid * 8;
          *(bf16x8*)&Klds[cb ^ 1][(e >> 6) * KSTR + (e & 63)] = kreg[c];
          *(bf16x8*)&Vtlds[cb ^ 1][(e >> 7) * VSTR + (e & 127)] = vreg[c];
        }
      }

      // O += P * V from buf[cb]
      __builtin_amdgcn_s_setprio(1);
#pragma unroll
      for (int kf16 = 0; kf16 < 8; kf16++) {
#pragma unroll
        for (int nd = 0; nd < 2; nd++) {
          bf16x8 vf = *(const bf16x8*)&Vtlds[cb][(nd * 32 + qi) * VSTR + kf16 * 16 + hf * 8];
          oacc[nd] = mfma32(pfrag[kf16], vf, oacc[nd]);
        }
      }
      __builtin_amdgcn_s_setprio(0);

      cb ^= 1;
    }

    float lsum = ls0 + ls1;
    lsum += __shfl_xor(lsum, 32);
    if (hf == 0) lp[(size_t)s * 65536 + bh * Tdim + tg] = lsum;

    u16* Ob = Op + (size_t)s * (32u * Tdim * HD) + ((size_t)bh * Tdim) * HD;
#pragma unroll
    for (int nd = 0; nd < 2; nd++) {
#pragma unroll
      for (int ri = 0; ri < 16; ri++) {
        const int rq = (ri & 3) + 8 * (ri >> 2) + 4 * hf;
        const int t = q0 + w * 32 + rq;
        Ob[(size_t)t * HD + nd * 32 + qi] = f2bf(oacc[nd][ri]);
      }
    }
  }
}

// ---------------- output projection GEMM with FUSED merge/normalize A-path (v2) ----------------
// (unchanged from round 9: M-major XCD chunking keeps per-XCD Opart slab
// L2-resident; T14 issue-early Op/lp prefetch retires under MFMA.)
__global__ __launch_bounds__(256, 2) void gemm_out(
    const u16* __restrict__ Op, const float* __restrict__ lp,
    const u16* __restrict__ WoT, const float* __restrict__ bo,
    float* __restrict__ C) {
  const int flat = blockIdx.x + 64 * blockIdx.y;
  const int c = flat & 7, j = flat >> 3;      // physical xcd = flat&7
  const int lbx = c * 8 + (j & 7);            // M-slab per XCD
  const int lby = j >> 3;

  __shared__ alignas(16) u16 Alds[64 * 64];
  __shared__ alignas(16) u16 Blds[128 * 64];
  const int tid = threadIdx.x;
  const int w = tid >> 6, lane = tid & 63, ln = lane & 15, quad = lane >> 4;
  const int tm = lbx * 64, tn = lby * 128;

  f32x4 acc[4][2] = {};

  const int srow = lane >> 3;
  const int scol = ((lane & 7) ^ srow) * 8;
  const u16* bg0 = WoT + (size_t)(tn + w * 32 + srow) * Ddim + scol;

  const int ar = tid >> 3;          // 0..31
  const int ac8 = tid & 7;          // octet 0..7 within the 64-col K-tile
  const int row0 = tm + ar, row1 = tm + ar + 32;
  const int b0r = row0 >> 11, t0r = row0 & 2047;
  const int b1r = row1 >> 11, t1r = row1 & 2047;
  const size_t pstr = (size_t)32 * Tdim * HD;
  const int aslot = (ac8 ^ (ar & 7)) * 8;  // (ar+32)&7 == ar&7

  u32x4 a00, a01, a10, a11;
  float l0a, l0b, l1a, l1b;
#define LOADA(H)                                                              \
  {                                                                           \
    const int bh0 = b0r * Hn + (H), bh1 = b1r * Hn + (H);                     \
    const size_t o0 = ((size_t)bh0 * Tdim + t0r) * HD + ac8 * 8;              \
    const size_t o1 = ((size_t)bh1 * Tdim + t1r) * HD + ac8 * 8;              \
    a00 = *(const u32x4*)&Op[o0];                                             \
    a01 = *(const u32x4*)&Op[pstr + o0];                                      \
    a10 = *(const u32x4*)&Op[o1];                                             \
    a11 = *(const u32x4*)&Op[pstr + o1];                                      \
    l0a = lp[bh0 * Tdim + t0r]; l0b = lp[65536 + bh0 * Tdim + t0r];           \
    l1a = lp[bh1 * Tdim + t1r]; l1b = lp[65536 + bh1 * Tdim + t1r];           \
  }

  LOADA(0);

  for (int k0 = 0; k0 < Ddim; k0 += 64) {
    __syncthreads();
#pragma unroll
    for (int jj = 0; jj < 4; jj++)
      cp16(bg0 + (size_t)jj * 8 * Ddim + k0, &Blds[(w * 32 + jj * 8) * 64]);
    {
      const float inv0 = 1.0f / (l0a + l0b);
      const float inv1 = 1.0f / (l1a + l1b);
      u32x4 q0, q1;
#pragma unroll
      for (int jj = 0; jj < 4; jj++) {
        const float lo0 = bf2f((u16)(a00[jj] & 0xffffu)) + bf2f((u16)(a01[jj] & 0xffffu));
        const float hi0 = bf2f((u16)(a00[jj] >> 16)) + bf2f((u16)(a01[jj] >> 16));
        q0[jj] = cvtpk_bf16(lo0 * inv0, hi0 * inv0);
        const float lo1 = bf2f((u16)(a10[jj] & 0xffffu)) + bf2f((u16)(a11[jj] & 0xffffu));
        const float hi1 = bf2f((u16)(a10[jj] >> 16)) + bf2f((u16)(a11[jj] >> 16));
        q1[jj] = cvtpk_bf16(lo1 * inv1, hi1 * inv1);
      }
      *(u32x4*)&Alds[ar * 64 + aslot] = q0;
      *(u32x4*)&Alds[(ar + 32) * 64 + aslot] = q1;
    }
    __syncthreads();
    if (k0 + 64 < Ddim) LOADA((k0 >> 6) + 1);  // retire under MFMA below
#pragma unroll
    for (int k2 = 0; k2 < 2; k2++) {
      const int so = ((k2 * 4 + quad) ^ (ln & 7)) * 8;
      bf16x8 af[4], bfr[2];
#pragma unroll
      for (int i = 0; i < 4; i++)
        af[i] = *(const bf16x8*)&Alds[(i * 16 + ln) * 64 + so];
#pragma unroll
      for (int i = 0; i < 2; i++)
        bfr[i] = *(const bf16x8*)&Blds[(w * 32 + i * 16 + ln) * 64 + so];
#pragma unroll
      for (int mi = 0; mi < 4; mi++)
#pragma unroll
        for (int ni = 0; ni < 2; ni++)
          acc[mi][ni] = mfma16(af[mi], bfr[ni], acc[mi][ni]);
    }
  }
#undef LOADA

#pragma unroll
  for (int mi = 0; mi < 4; mi++) {
#pragma unroll
    for (int ni = 0; ni < 2; ni++) {
      const int gm0 = tm + mi * 16 + quad * 4;
      const int gn = tn + w * 32 + ni * 16 + ln;
      const float bv_ = bo[gn];
#pragma unroll
      for (int r = 0; r < 4; r++)
        C[(size_t)(gm0 + r) * Ddim + gn] = acc[mi][ni][r] + bv_;
    }
  }
}

extern "C" void kernel_launch(void* const* d_in, const int* in_sizes, int n_in,
                              void* d_out, int out_size, void* d_ws, size_t ws_size,
                              hipStream_t stream) {
  (void)in_sizes; (void)n_in; (void)out_size; (void)ws_size;
  const float* x  = (const float*)d_in[0];
  const float* Wq = (const float*)d_in[1];
  const float* bq = (const float*)d_in[2];
  const float* Wk = (const float*)d_in[3];
  const float* bk = (const float*)d_in[4];
  const float* Wv = (const float*)d_in[5];
  const float* bv = (const float*)d_in[6];
  const float* Wo = (const float*)d_in[7];
  const float* bo = (const float*)d_in[8];

  char* ws = (char*)d_ws;
  const size_t MB = 1024 * 1024;
  u16* WT   = (u16*)(ws + 0 * MB);   // 8MB: WqT, WkT, WvT, WoT (z-major)
  u16* Qb   = (u16*)(ws + 8 * MB);   // 8MB bf16 (B,H,T,64)
  u16* Kb   = (u16*)(ws + 16 * MB);
  u16* Vtb  = (u16*)(ws + 24 * MB);  // 8MB bf16 (B,H,64,T)
  u16* Xb   = (u16*)(ws + 32 * MB);  // 8MB bf16 X
  u16* Opart= (u16*)(ws + 40 * MB);  // 16MB: 2 x (BH,T,64) bf16 partial O
  float* lpart = (float*)(ws + 56 * MB); // 512KB: 2 x (BH,T) f32 partial l
  u16* WoT = WT + (size_t)3 * Ddim * Ddim;

  preproc_k<<<dim3(32, 32, 5), dim3(32, 8), 0, stream>>>(x, Xb, Wq, Wk, Wv, Wo, WT);
  gemm_qkv<<<dim3(32, 8, 3), 256, 0, stream>>>(Xb, WT, bq, bk, bv, Qb, Kb, Vtb);
  attn_k<<<dim3(512), 256, 0, stream>>>(Qb, Kb, Vtb, Opart, lpart);
  gemm_out<<<dim3(64, 8), 256, 0, stream>>>(Opart, lpart, WoT, bo, (float*)d_out);
}

// Round 11
// 180.274 us; speedup vs baseline: 1.0051x; 1.0051x over previous
//
#include <hip/hip_runtime.h>
#include <hip/hip_bf16.h>

// Problem constants
#define Bn 2
#define Tdim 2048
#define Ddim 1024
#define Hn 16
#define HD 64

typedef unsigned short u16;
typedef unsigned int u32;
typedef __attribute__((ext_vector_type(8))) __bf16 bf16x8;
typedef __attribute__((ext_vector_type(4))) float f32x4;
typedef __attribute__((ext_vector_type(16))) float f32x16;
typedef __attribute__((ext_vector_type(4))) u32 u32x4;

struct alignas(8) U16x4 { u16 x, y, z, w; };

__device__ __forceinline__ u16 f2bf(float f) {
  union { float f; u32 i; } v; v.f = f;
  u32 x = v.i;
  u32 r = (x + 0x7fffu + ((x >> 16) & 1u)) >> 16;
  return (u16)r;
}
__device__ __forceinline__ float bf2f(u16 u) {
  union { u32 i; float f; } v; v.i = ((u32)u) << 16; return v.f;
}

// packed f32->bf16 convert: dst.lo16 = bf16(a), dst.hi16 = bf16(b) (RNE)
__device__ __forceinline__ u32 cvtpk_bf16(float a, float b) {
  u32 d;
  asm("v_cvt_pk_bf16_f32 %0, %1, %2" : "=v"(d) : "v"(a), "v"(b));
  return d;
}

// async global->LDS, 16B per lane; LDS dest = wave-uniform base + lane*16
__device__ __forceinline__ void cp16(const u16* g, u16* l) {
  __builtin_amdgcn_global_load_lds(
      (const __attribute__((address_space(1))) u32*)g,
      (__attribute__((address_space(3))) u32*)l, 16, 0, 0);
}

__device__ __forceinline__ f32x4 mfma16(bf16x8 a, bf16x8 b, f32x4 c) {
  return __builtin_amdgcn_mfma_f32_16x16x32_bf16(a, b, c, 0, 0, 0);
}
__device__ __forceinline__ f32x16 mfma32(bf16x8 a, bf16x8 b, f32x16 c) {
  return __builtin_amdgcn_mfma_f32_32x32x16_bf16(a, b, c, 0, 0, 0);
}

// ---------------- fused preprocessing: weight transpose (z=0..3) + X convert (z=4) ----------------
// Transpose write phase now uses paired-column u32 stores (2 elems/store,
// 16 lanes = 64B contiguous per output row) instead of 2B scalar stores.
__global__ __launch_bounds__(256) void preproc_k(
    const float* __restrict__ x, u16* __restrict__ Xb,
    const float* __restrict__ s0, const float* __restrict__ s1,
    const float* __restrict__ s2, const float* __restrict__ s3,
    u16* __restrict__ dstW) {
  const int tx = threadIdx.x, ty = threadIdx.y;
  const int tid = ty * 32 + tx;
  if (blockIdx.z == 4) {
    // X f32 -> bf16, 16 elems/thread
    const int i = ((blockIdx.y * 32 + blockIdx.x) * 256 + tid) * 16;
#pragma unroll
    for (int c = 0; c < 2; c++) {
      u16 t[8];
#pragma unroll
      for (int j = 0; j < 8; j++) t[j] = f2bf(x[i + c * 8 + j]);
      *(bf16x8*)&Xb[i + c * 8] = *(const bf16x8*)t;
    }
    return;
  }
  const float* src = (blockIdx.z == 0) ? s0 : (blockIdx.z == 1) ? s1
                   : (blockIdx.z == 2) ? s2 : s3;
  u16* d = dstW + (size_t)blockIdx.z * Ddim * Ddim;
  __shared__ u16 tile[32][33];
  const int xx = blockIdx.x * 32 + tx;
  const int y0 = blockIdx.y * 32;
#pragma unroll
  for (int j = 0; j < 32; j += 8) tile[ty + j][tx] = f2bf(src[(size_t)(y0 + ty + j) * Ddim + xx]);
  __syncthreads();
  // write: out(row = bx*32 + r, col = by*32 + c) = tile[c][r]; u32 packs c,c+1
  const int c2 = (tid & 15) * 2;
  const int rr = tid >> 4;  // 0..15
  const int yo0 = blockIdx.x * 32;
  const int xo0 = blockIdx.y * 32;
#pragma unroll
  for (int j = 0; j < 2; j++) {
    const int r = rr + 16 * j;
    const u32 vlo = tile[c2][r], vhi = tile[c2 + 1][r];
    *(u32*)&d[(size_t)(yo0 + r) * Ddim + xo0 + c2] = vlo | (vhi << 16);
  }
}

// ---------------- fused QKV projection GEMM: 128x128, BK=64, swizzled LDS ----------------
// z<2 (Q/K) uses SWAPPED MFMA operand order (legal: A/B fragments are
// layout-symmetric for 16x16x32): acc regs then hold 4 consecutive d values
// -> packed U16x4 stores (16x8B) instead of 64 scalar 2B stores.
// z==2 (V^T) keeps the original order (regs = 4 consecutive t, packed along t).
__global__ __launch_bounds__(256, 2) void gemm_qkv(
    const u16* __restrict__ Xb, const u16* __restrict__ WT,
    const float* __restrict__ bq, const float* __restrict__ bk, const float* __restrict__ bv,
    u16* __restrict__ Q, u16* __restrict__ K, u16* __restrict__ Vt) {
  const int flat = blockIdx.x + 32 * (blockIdx.y + 8 * blockIdx.z);
  const int l = (flat & 7) * 96 + (flat >> 3);
  const int lbx = l & 31, lby = (l >> 5) & 7, z = l >> 8;

  const u16* Wt = WT + (size_t)z * Ddim * Ddim;
  const float* bias = (z == 0) ? bq : (z == 1) ? bk : bv;
  u16* QK = (z == 0) ? Q : K;

  __shared__ alignas(16) u16 Alds[128 * 64];
  __shared__ alignas(16) u16 Blds[128 * 64];
  const int tid = threadIdx.x;
  const int w = tid >> 6, lane = tid & 63, ln = lane & 15, quad = lane >> 4;
  const int wm = (w >> 1) * 64, wn = (w & 1) * 64;
  const int tm = lbx * 128, tn = lby * 128;

  f32x4 acc[4][4] = {};

  const int srow = lane >> 3;                    // 0..7
  const int scol = ((lane & 7) ^ srow) * 8;      // inverse swizzle on source
  const u16* ag0 = Xb + (size_t)(tm + w * 32 + srow) * Ddim + scol;
  const u16* bg0 = Wt + (size_t)(tn + w * 32 + srow) * Ddim + scol;

#define QKV_KLOOP(MFMA_EXPR)                                                  \
  for (int k0 = 0; k0 < Ddim; k0 += 64) {                                     \
    __syncthreads();                                                          \
    _Pragma("unroll")                                                         \
    for (int j = 0; j < 4; j++) {                                             \
      cp16(ag0 + (size_t)j * 8 * Ddim + k0, &Alds[(w * 32 + j * 8) * 64]);    \
      cp16(bg0 + (size_t)j * 8 * Ddim + k0, &Blds[(w * 32 + j * 8) * 64]);    \
    }                                                                         \
    __syncthreads();                                                          \
    _Pragma("unroll")                                                         \
    for (int k2 = 0; k2 < 2; k2++) {                                          \
      const int so = ((k2 * 4 + quad) ^ (ln & 7)) * 8;                        \
      bf16x8 af[4], bfr[4];                                                   \
      _Pragma("unroll")                                                       \
      for (int i = 0; i < 4; i++)                                             \
        af[i] = *(const bf16x8*)&Alds[(wm + i * 16 + ln) * 64 + so];          \
      _Pragma("unroll")                                                       \
      for (int i = 0; i < 4; i++)                                             \
        bfr[i] = *(const bf16x8*)&Blds[(wn + i * 16 + ln) * 64 + so];         \
      _Pragma("unroll")                                                       \
      for (int mi = 0; mi < 4; mi++)                                          \
        _Pragma("unroll")                                                     \
        for (int ni = 0; ni < 4; ni++)                                        \
          acc[mi][ni] = MFMA_EXPR;                                            \
    }                                                                         \
  }

  if (z < 2) {
    QKV_KLOOP(mfma16(bfr[ni], af[mi], acc[mi][ni]))
    // epilogue: regs r=0..3 hold consecutive d at fixed t=...+ln
    float bv4[4][4];
#pragma unroll
    for (int ni = 0; ni < 4; ni++)
#pragma unroll
      for (int r = 0; r < 4; r++)
        bv4[ni][r] = bias[tn + wn + ni * 16 + quad * 4 + r];
#pragma unroll
    for (int mi = 0; mi < 4; mi++) {
      const int gm = tm + wm + mi * 16 + ln;
      const int b0 = gm >> 11, t0 = gm & 2047;
#pragma unroll
      for (int ni = 0; ni < 4; ni++) {
        const int gnq = tn + wn + ni * 16 + quad * 4;
        const int hh = gnq >> 6, dd = gnq & 63;
        U16x4 pk;
        pk.x = f2bf(acc[mi][ni][0] + bv4[ni][0]);
        pk.y = f2bf(acc[mi][ni][1] + bv4[ni][1]);
        pk.z = f2bf(acc[mi][ni][2] + bv4[ni][2]);
        pk.w = f2bf(acc[mi][ni][3] + bv4[ni][3]);
        *(U16x4*)&QK[((size_t)(b0 * Hn + hh) * Tdim + t0) * HD + dd] = pk;
      }
    }
  } else {
    QKV_KLOOP(mfma16(af[mi], bfr[ni], acc[mi][ni]))
    // epilogue: regs r=0..3 hold consecutive t at fixed d -> packed along t
#pragma unroll
    for (int mi = 0; mi < 4; mi++) {
#pragma unroll
      for (int ni = 0; ni < 4; ni++) {
        const int gm0 = tm + wm + mi * 16 + quad * 4;
        const int gn = tn + wn + ni * 16 + ln;
        const float bv_ = bias[gn];
        const int hh = gn >> 6, dd = gn & 63;
        const int b0 = gm0 >> 11, t0 = gm0 & 2047;
        U16x4 pk;
        pk.x = f2bf(acc[mi][ni][0] + bv_);
        pk.y = f2bf(acc[mi][ni][1] + bv_);
        pk.z = f2bf(acc[mi][ni][2] + bv_);
        pk.w = f2bf(acc[mi][ni][3] + bv_);
        *(U16x4*)&Vt[((size_t)(b0 * Hn + hh) * HD + dd) * Tdim + t0] = pk;
      }
    }
  }
#undef QKV_KLOOP
}

// ---------------- flash attention (round-9 anchor): triangle-folded pairing + bh-grouped XCD swizzle ----------------
// Single-buffer, 2 barriers/tile. Measured best (180.4 total). Round-10 dbuf
// variant was neutral-to-noise-worse; attn is VALU/TRANS+MFMA joint-bound
// (~35us floor), not barrier-bound — structural experiments closed.
#define KSTR 68
#define VSTR 132
#define L2E 1.44269504088896f
__global__ __launch_bounds__(256, 2) void attn_k(
    const u16* __restrict__ Q, const u16* __restrict__ K, const u16* __restrict__ Vt,
    u16* __restrict__ Op, float* __restrict__ lp) {
  __shared__ alignas(16) u16 Klds[128 * KSTR];
  __shared__ alignas(16) u16 Vtlds[64 * VSTR];

  const int id = blockIdx.x;
  const int xcd = id & 7, slot = id >> 3;
  const int bh = (xcd << 2) | (slot >> 4);
  const int inner = slot & 15;
  const int p = inner >> 1;
  const int s = inner & 1;
  const int tid = threadIdx.x;
  const int w = tid >> 6, lane = tid & 63;
  const int qi = lane & 31, hf = lane >> 5;

  const u16* Qh = Q + (size_t)bh * Tdim * HD;
  const u16* Kh = K + (size_t)bh * Tdim * HD;
  const u16* Vh = Vt + (size_t)bh * HD * Tdim;
  const float slope = exp2f(-0.5f * (float)((bh & 15) + 1));

  const float sl2 = slope * L2E;
  const float c1 = 0.125f * L2E;
  const float f4hf = (float)(4 * hf);
  float sg8[4], slm[4];
#pragma unroll
  for (int g = 0; g < 4; g++) sg8[g] = sl2 * (float)(8 * g);
#pragma unroll
  for (int m = 0; m < 4; m++) slm[m] = sl2 * (float)m;

  const int qbs[2] = {p, 15 - p};
  int K0[2], K1[2];
#pragma unroll
  for (int seg = 0; seg < 2; seg++) {
    const int nk = qbs[seg] + 1;
    const int h0 = (nk + 1) >> 1;
    K0[seg] = s ? h0 : 0;
    K1[seg] = s ? nk : h0;
  }

  bf16x8 kreg[4], vreg[4];
  {
    const int kb = ((K0[0] < K1[0]) ? K0[0] : K0[1]) * 128;
#pragma unroll
    for (int c = 0; c < 4; c++) {
      const int e = c * 2048 + tid * 8;
      kreg[c] = *(const bf16x8*)&Kh[(size_t)(kb + (e >> 6)) * HD + (e & 63)];
      vreg[c] = *(const bf16x8*)&Vh[(size_t)(e >> 7) * Tdim + kb + (e & 127)];
    }
  }

  for (int seg = 0; seg < 2; seg++) {
    const int qb = qbs[seg];
    const int kt0 = K0[seg], kt1 = K1[seg];
    const int nkt = qb + 1;
    const int q0 = qb * 128;
    const int tg = q0 + w * 32 + qi;
    const float tt2 = (slope * (float)tg + 3.0f) * L2E;

    bf16x8 qf[4];
#pragma unroll
    for (int kc = 0; kc < 4; kc++)
      qf[kc] = *(const bf16x8*)&Qh[(size_t)tg * HD + kc * 16 + hf * 8];

    float ls0 = 0.f, ls1 = 0.f;
    f32x16 oacc[2] = {};

    for (int kt = kt0; kt < kt1; kt++) {
      const int kb = kt * 128;
      __syncthreads();
#pragma unroll
      for (int c = 0; c < 4; c++) {
        const int e = c * 2048 + tid * 8;
        *(bf16x8*)&Klds[(e >> 6) * KSTR + (e & 63)] = kreg[c];
        *(bf16x8*)&Vtlds[(e >> 7) * VSTR + (e & 127)] = vreg[c];
      }
      __syncthreads();

      {
        const int nxt = (kt + 1 < kt1) ? (kt + 1) : ((seg == 0) ? K0[1] : -1);
        if (nxt >= 0) {
          const int kb2 = nxt * 128;
#pragma unroll
          for (int c = 0; c < 4; c++) {
            const int e = c * 2048 + tid * 8;
            kreg[c] = *(const bf16x8*)&Kh[(size_t)(kb2 + (e >> 6)) * HD + (e & 63)];
            vreg[c] = *(const bf16x8*)&Vh[(size_t)(e >> 7) * Tdim + kb2 + (e & 127)];
          }
        }
      }

      // S^T = K Q^T
      f32x16 st[4] = {};
      __builtin_amdgcn_s_setprio(1);
#pragma unroll
      for (int kc = 0; kc < 4; kc++) {
#pragma unroll
        for (int ni = 0; ni < 4; ni++) {
          bf16x8 kf = *(const bf16x8*)&Klds[(ni * 32 + qi) * KSTR + kc * 16 + hf * 8];
          st[ni] = mfma32(kf, qf[kc], st[ni]);
        }
      }
      __builtin_amdgcn_s_setprio(0);

      const bool diag = (kt == nkt - 1);
      const float fkb = (float)kb + f4hf;
      bf16x8 pfrag[8];
#pragma unroll
      for (int ni = 0; ni < 4; ni++) {
        const float cni = __builtin_fmaf(sl2, fkb + (float)(32 * ni), -tt2);
        float pv[16];
        if (!diag) {
#pragma unroll
          for (int ri = 0; ri < 16; ri++) {
            const float e = __builtin_fmaf(st[ni][ri], c1, cni + sg8[ri >> 2] + slm[ri & 3]);
            const float pp = __builtin_amdgcn_exp2f(e);
            if (ri & 1) ls1 += pp; else ls0 += pp;
            pv[ri] = pp;
          }
        } else {
#pragma unroll
          for (int ri = 0; ri < 16; ri++) {
            const int n = kb + ni * 32 + (ri & 3) + 8 * (ri >> 2) + 4 * hf;
            const float e = __builtin_fmaf(st[ni][ri], c1, cni + sg8[ri >> 2] + slm[ri & 3]);
            float pp = __builtin_amdgcn_exp2f(e);
            if (n > tg) pp = 0.f;
            if (ri & 1) ls1 += pp; else ls0 += pp;
            pv[ri] = pp;
          }
        }
        u32 pk[4][2];
#pragma unroll
        for (int g = 0; g < 4; g++) {
          pk[g][0] = cvtpk_bf16(pv[g * 4 + 0], pv[g * 4 + 1]);
          pk[g][1] = cvtpk_bf16(pv[g * 4 + 2], pv[g * 4 + 3]);
        }
#pragma unroll
        for (int a = 0; a < 2; a++) {
          const u32 snd0 = (hf == 0) ? pk[2 * a + 1][0] : pk[2 * a][0];
          const u32 snd1 = (hf == 0) ? pk[2 * a + 1][1] : pk[2 * a][1];
          const u32 rcv0 = (u32)__shfl_xor((int)snd0, 32);
          const u32 rcv1 = (u32)__shfl_xor((int)snd1, 32);
          u32x4 fr;
          fr.x = (hf == 0) ? pk[2 * a][0] : rcv0;
          fr.y = (hf == 0) ? pk[2 * a][1] : rcv1;
          fr.z = (hf == 0) ? rcv0 : pk[2 * a + 1][0];
          fr.w = (hf == 0) ? rcv1 : pk[2 * a + 1][1];
          pfrag[ni * 2 + a] = *(bf16x8*)&fr;
        }
      }

      // O += P * V
      __builtin_amdgcn_s_setprio(1);
#pragma unroll
      for (int kf16 = 0; kf16 < 8; kf16++) {
#pragma unroll
        for (int nd = 0; nd < 2; nd++) {
          bf16x8 vf = *(const bf16x8*)&Vtlds[(nd * 32 + qi) * VSTR + kf16 * 16 + hf * 8];
          oacc[nd] = mfma32(pfrag[kf16], vf, oacc[nd]);
        }
      }
      __builtin_amdgcn_s_setprio(0);
    }

    float lsum = ls0 + ls1;
    lsum += __shfl_xor(lsum, 32);
    if (hf == 0) lp[(size_t)s * 65536 + bh * Tdim + tg] = lsum;

    u16* Ob = Op + (size_t)s * (32u * Tdim * HD) + ((size_t)bh * Tdim) * HD;
#pragma unroll
    for (int nd = 0; nd < 2; nd++) {
#pragma unroll
      for (int ri = 0; ri < 16; ri++) {
        const int rq = (ri & 3) + 8 * (ri >> 2) + 4 * hf;
        const int t = q0 + w * 32 + rq;
        Ob[(size_t)t * HD + nd * 32 + qi] = f2bf(oacc[nd][ri]);
      }
    }
  }
}

// ---------------- output projection GEMM with FUSED merge/normalize A-path (v2) ----------------
// (unchanged from round 9: M-major XCD chunking keeps per-XCD Opart slab
// L2-resident; T14 issue-early Op/lp prefetch retires under MFMA.)
__global__ __launch_bounds__(256, 2) void gemm_out(
    const u16* __restrict__ Op, const float* __restrict__ lp,
    const u16* __restrict__ WoT, const float* __restrict__ bo,
    float* __restrict__ C) {
  const int flat = blockIdx.x + 64 * blockIdx.y;
  const int c = flat & 7, j = flat >> 3;      // physical xcd = flat&7
  const int lbx = c * 8 + (j & 7);            // M-slab per XCD
  const int lby = j >> 3;

  __shared__ alignas(16) u16 Alds[64 * 64];
  __shared__ alignas(16) u16 Blds[128 * 64];
  const int tid = threadIdx.x;
  const int w = tid >> 6, lane = tid & 63, ln = lane & 15, quad = lane >> 4;
  const int tm = lbx * 64, tn = lby * 128;

  f32x4 acc[4][2] = {};

  const int srow = lane >> 3;
  const int scol = ((lane & 7) ^ srow) * 8;
  const u16* bg0 = WoT + (size_t)(tn + w * 32 + srow) * Ddim + scol;

  const int ar = tid >> 3;          // 0..31
  const int ac8 = tid & 7;          // octet 0..7 within the 64-col K-tile
  const int row0 = tm + ar, row1 = tm + ar + 32;
  const int b0r = row0 >> 11, t0r = row0 & 2047;
  const int b1r = row1 >> 11, t1r = row1 & 2047;
  const size_t pstr = (size_t)32 * Tdim * HD;
  const int aslot = (ac8 ^ (ar & 7)) * 8;  // (ar+32)&7 == ar&7

  u32x4 a00, a01, a10, a11;
  float l0a, l0b, l1a, l1b;
#define LOADA(H)                                                              \
  {                                                                           \
    const int bh0 = b0r * Hn + (H), bh1 = b1r * Hn + (H);                     \
    const size_t o0 = ((size_t)bh0 * Tdim + t0r) * HD + ac8 * 8;              \
    const size_t o1 = ((size_t)bh1 * Tdim + t1r) * HD + ac8 * 8;              \
    a00 = *(const u32x4*)&Op[o0];                                             \
    a01 = *(const u32x4*)&Op[pstr + o0];                                      \
    a10 = *(const u32x4*)&Op[o1];                                             \
    a11 = *(const u32x4*)&Op[pstr + o1];                                      \
    l0a = lp[bh0 * Tdim + t0r]; l0b = lp[65536 + bh0 * Tdim + t0r];           \
    l1a = lp[bh1 * Tdim + t1r]; l1b = lp[65536 + bh1 * Tdim + t1r];           \
  }

  LOADA(0);

  for (int k0 = 0; k0 < Ddim; k0 += 64) {
    __syncthreads();
#pragma unroll
    for (int jj = 0; jj < 4; jj++)
      cp16(bg0 + (size_t)jj * 8 * Ddim + k0, &Blds[(w * 32 + jj * 8) * 64]);
    {
      const float inv0 = 1.0f / (l0a + l0b);
      const float inv1 = 1.0f / (l1a + l1b);
      u32x4 q0, q1;
#pragma unroll
      for (int jj = 0; jj < 4; jj++) {
        const float lo0 = bf2f((u16)(a00[jj] & 0xffffu)) + bf2f((u16)(a01[jj] & 0xffffu));
        const float hi0 = bf2f((u16)(a00[jj] >> 16)) + bf2f((u16)(a01[jj] >> 16));
        q0[jj] = cvtpk_bf16(lo0 * inv0, hi0 * inv0);
        const float lo1 = bf2f((u16)(a10[jj] & 0xffffu)) + bf2f((u16)(a11[jj] & 0xffffu));
        const float hi1 = bf2f((u16)(a10[jj] >> 16)) + bf2f((u16)(a11[jj] >> 16));
        q1[jj] = cvtpk_bf16(lo1 * inv1, hi1 * inv1);
      }
      *(u32x4*)&Alds[ar * 64 + aslot] = q0;
      *(u32x4*)&Alds[(ar + 32) * 64 + aslot] = q1;
    }
    __syncthreads();
    if (k0 + 64 < Ddim) LOADA((k0 >> 6) + 1);  // retire under MFMA below
#pragma unroll
    for (int k2 = 0; k2 < 2; k2++) {
      const int so = ((k2 * 4 + quad) ^ (ln & 7)) * 8;
      bf16x8 af[4], bfr[2];
#pragma unroll
      for (int i = 0; i < 4; i++)
        af[i] = *(const bf16x8*)&Alds[(i * 16 + ln) * 64 + so];
#pragma unroll
      for (int i = 0; i < 2; i++)
        bfr[i] = *(const bf16x8*)&Blds[(w * 32 + i * 16 + ln) * 64 + so];
#pragma unroll
      for (int mi = 0; mi < 4; mi++)
#pragma unroll
        for (int ni = 0; ni < 2; ni++)
          acc[mi][ni] = mfma16(af[mi], bfr[ni], acc[mi][ni]);
    }
  }
#undef LOADA

#pragma unroll
  for (int mi = 0; mi < 4; mi++) {
#pragma unroll
    for (int ni = 0; ni < 2; ni++) {
      const int gm0 = tm + mi * 16 + quad * 4;
      const int gn = tn + w * 32 + ni * 16 + ln;
      const float bv_ = bo[gn];
#pragma unroll
      for (int r = 0; r < 4; r++)
        C[(size_t)(gm0 + r) * Ddim + gn] = acc[mi][ni][r] + bv_;
    }
  }
}

extern "C" void kernel_launch(void* const* d_in, const int* in_sizes, int n_in,
                              void* d_out, int out_size, void* d_ws, size_t ws_size,
                              hipStream_t stream) {
  (void)in_sizes; (void)n_in; (void)out_size; (void)ws_size;
  const float* x  = (const float*)d_in[0];
  const float* Wq = (const float*)d_in[1];
  const float* bq = (const float*)d_in[2];
  const float* Wk = (const float*)d_in[3];
  const float* bk = (const float*)d_in[4];
  const float* Wv = (const float*)d_in[5];
  const float* bv = (const float*)d_in[6];
  const float* Wo = (const float*)d_in[7];
  const float* bo = (const float*)d_in[8];

  char* ws = (char*)d_ws;
  const size_t MB = 1024 * 1024;
  u16* WT   = (u16*)(ws + 0 * MB);   // 8MB: WqT, WkT, WvT, WoT (z-major)
  u16* Qb   = (u16*)(ws + 8 * MB);   // 8MB bf16 (B,H,T,64)
  u16* Kb   = (u16*)(ws + 16 * MB);
  u16* Vtb  = (u16*)(ws + 24 * MB);  // 8MB bf16 (B,H,64,T)
  u16* Xb   = (u16*)(ws + 32 * MB);  // 8MB bf16 X
  u16* Opart= (u16*)(ws + 40 * MB);  // 16MB: 2 x (BH,T,64) bf16 partial O
  float* lpart = (float*)(ws + 56 * MB); // 512KB: 2 x (BH,T) f32 partial l
  u16* WoT = WT + (size_t)3 * Ddim * Ddim;

  preproc_k<<<dim3(32, 32, 5), dim3(32, 8), 0, stream>>>(x, Xb, Wq, Wk, Wv, Wo, WT);
  gemm_qkv<<<dim3(32, 8, 3), 256, 0, stream>>>(Xb, WT, bq, bk, bv, Qb, Kb, Vtb);
  attn_k<<<dim3(512), 256, 0, stream>>>(Qb, Kb, Vtb, Opart, lpart);
  gemm_out<<<dim3(64, 8), 256, 0, stream>>>(Opart, lpart, WoT, bo, (float*)d_out);
}